// Round 9
// baseline (272.855 us; speedup 1.0000x reference)
//
#include <hip/hip_runtime.h>
#include <hip/hip_bf16.h>
#include <cmath>

#define T_SEQ 2048
#define NHEADS 16
#define DHEAD 64
#define DMODEL 1024
#define CQKV 3072

typedef __attribute__((ext_vector_type(8))) short short8;
typedef __attribute__((ext_vector_type(8))) __bf16 bf16x8;
typedef __attribute__((ext_vector_type(4))) float floatx4;

#define LDS_CAST(p) ((__attribute__((address_space(3))) void*)(p))
#define GLB_CAST(p) ((const __attribute__((address_space(1))) void*)(p))

static __device__ __forceinline__ floatx4 mfma_bf16(short8 a, short8 b, floatx4 c) {
  return __builtin_amdgcn_mfma_f32_16x16x32_bf16(
      __builtin_bit_cast(bf16x8, a), __builtin_bit_cast(bf16x8, b), c, 0, 0, 0);
}

// fp32 -> bf16 round-to-nearest-even, bit carrier = short
static __device__ __forceinline__ short f2bf(float f) {
  union { float f; unsigned u; } x; x.f = f;
  unsigned r = x.u + 0x7FFFu + ((x.u >> 16) & 1u);
  return (short)(r >> 16);
}

static __device__ __forceinline__ float bf2f(short s) {
  return __builtin_bit_cast(float, ((unsigned)(unsigned short)s) << 16);
}

static __device__ __forceinline__ float exp2_(float x) {
#if __has_builtin(__builtin_amdgcn_exp2f)
  return __builtin_amdgcn_exp2f(x);
#else
  return exp2f(x);
#endif
}

// bf16 vs fp32 input sniff (round-1 notes). 16-of-32 exponent vote.
static __device__ __forceinline__ bool sniff_is_bf16(const unsigned* __restrict__ x) {
  int cnt = 0;
#pragma unroll
  for (int i = 0; i < 32; ++i) {
    unsigned e = (x[i] >> 7) & 0xFFu;
    cnt += (e >= 0x70u && e <= 0x8Fu) ? 1 : 0;
  }
  return cnt >= 16;
}

static __device__ __forceinline__ short8 load8f32(const char* p, size_t idx) {
  const float4* f = (const float4*)(p + idx * 4);
  float4 a = f[0], b = f[1];
  short8 r;
  r[0] = f2bf(a.x); r[1] = f2bf(a.y); r[2] = f2bf(a.z); r[3] = f2bf(a.w);
  r[4] = f2bf(b.x); r[5] = f2bf(b.y); r[6] = f2bf(b.z); r[7] = f2bf(b.w);
  return r;
}

// ---- fused preprocessing: conv_x + tpose(w_qkv) + tpose(w_proj) -----------
// blockIdx.x ranges:
//   [0, 4096)            : x -> bf16 copy/convert (8 elems/thread)
//   [4096, 4096+3072)    : w_qkv [1024,3072] -> wqkvT [3072,1024]
//   [7168, 7168+1024)    : w_proj [1024,1024] -> wprojT [1024,1024]
__global__ __launch_bounds__(256) void prep(const char* __restrict__ x,
                                            short* __restrict__ xbf,
                                            const char* __restrict__ wqkv,
                                            short* __restrict__ wqkvT,
                                            const char* __restrict__ wproj,
                                            short* __restrict__ wprojT,
                                            const unsigned* __restrict__ xs) {
  const bool isbf = sniff_is_bf16(xs);
  const int bid = blockIdx.x;
  if (bid < 4096) {
    const int i = (bid * 256 + threadIdx.x) * 8;
    if (isbf) *(short8*)(xbf + i) = *(const short8*)((const short*)x + i);
    else      *(short8*)(xbf + i) = load8f32(x, (size_t)i);
    return;
  }
  // transpose part: 32x32 tile per block
  __shared__ short tile[32][33];
  const char* w; short* wt; int N, bid2;
  if (bid < 4096 + 3072) { w = wqkv;  wt = wqkvT;  N = 3072; bid2 = bid - 4096; }
  else                   { w = wproj; wt = wprojT; N = 1024; bid2 = bid - 7168; }
  const int K = 1024;
  const int ntiles = N >> 5;
  const int n0 = (bid2 % ntiles) * 32, k0 = (bid2 / ntiles) * 32;
  const int tx = threadIdx.x & 31, ty = threadIdx.x >> 5;  // 32 x 8
#pragma unroll
  for (int i = 0; i < 4; ++i) {
    const int r = ty * 4 + i;
    const size_t off = (size_t)(k0 + r) * N + n0 + tx;
    tile[r][tx] = isbf ? ((const short*)w)[off] : f2bf(((const float*)w)[off]);
  }
  __syncthreads();
#pragma unroll
  for (int i = 0; i < 4; ++i) {
    const int r = ty * 4 + i;
    wt[(size_t)(n0 + r) * K + k0 + tx] = tile[tx][r];
  }
}

// ---- GEMM v2: 128x128 tile, BK=32, DOUBLE-BUFFERED (1 barrier/iter) -------
// Round-8 analysis: the BK=64 2-barrier structure exposed a fresh vmcnt(0)
// DMA drain every iter (MfmaUtil 26%, VALUBusy 37%, HBM 15% -> drain-bound).
// This version applies the attn-v3 pattern AT CONSTANT LDS/OCCUPANCY:
//   as/bs[2][128*32] = 32 KB total (same as before) -> still 5 blocks/CU.
//   Per iter: sync (drains tile staged LAST iter -> latency hidden under a
//   full compute phase) -> stage next tile into other buffer -> compute.
// BK=32 rows are 64B, so the 8-chunk row swizzle degrades; instead rows are
// PAIR-INTERLEAVED: LDS line L (128B, 8x16B slots) holds rows 2L,2L+1.
//   slot s of line L stores u = s ^ (L&7), where u = (row&1)*4 + kchunk.
// Bank check: fragment read addr = line*128 + s*16, line stride 128B = 32
// banks -> bank depends on s only; per wave, each s value is hit exactly 2x
// (lm=l16>>1 spans 0..7 for each parity) -> 2 lanes/bank = conflict-free.
// Staging: chunk c (= tid, 256+tid) -> line c>>3, slot c&7; per-lane
// pre-swizzled GLOBAL source, linear wave-uniform LDS dest (base+lane*16).
// mode 0: C bf16 [M,N]; mode 1: dtype per sniff; mode 2: QKV split.
__global__ __launch_bounds__(256) void gemm128(const short* __restrict__ A,
                                               const short* __restrict__ Bt,
                                               void* __restrict__ C,
                                               short* __restrict__ C2,
                                               int M, int N, int K, int mode,
                                               const unsigned* __restrict__ xs) {
  const bool out_f32 = (mode == 1) ? !sniff_is_bf16(xs) : false;

  __shared__ short as[2][128 * 32];  // 8 KB per buffer
  __shared__ short bs[2][128 * 32];
  const int tid = threadIdx.x;
  const int wid = tid >> 6, lane = tid & 63;
  const int quad = lane >> 4, l16 = lane & 15;
  const int wm = wid >> 1, wn = wid & 1;
  const int m0 = blockIdx.y * 128, n0 = blockIdx.x * 128;

  // staging chunk map: c = tid (issue 0) / 256+tid (issue 1)
  // line cL=c>>3, slot cs=c&7, u=cs^(cL&7) -> row=2cL+(u>>2), kchunk=u&3.
  // issue 1: cL' = 32+cL -> cL'&7 == cL&7, row' = row+64, kchunk same.
  const int cL = tid >> 3, cs = tid & 7;
  const int cu = cs ^ (cL & 7);
  const int crow = 2 * cL + (cu >> 2);
  const int ckc8 = (cu & 3) * 8;

  // fragment slot: row = R0 + l16 (R0 mult of 16), kchunk = quad
  // -> line&7 = l16>>1, slot = ((l16&1)*4 + quad) ^ (l16>>1)
  const int lm = l16 >> 1;
  const int slotA = ((((l16 & 1) << 2) | quad) ^ lm) * 8;  // shorts

  const floatx4 zero4 = {0.f, 0.f, 0.f, 0.f};
  floatx4 acc[4][4];
#pragma unroll
  for (int i = 0; i < 4; ++i)
#pragma unroll
    for (int j = 0; j < 4; ++j) acc[i][j] = zero4;

  const short* a0 = A + (size_t)(m0 + crow) * K + ckc8;
  const short* a1 = A + (size_t)(m0 + crow + 64) * K + ckc8;
  const short* b0 = Bt + (size_t)(n0 + crow) * K + ckc8;
  const short* b1 = Bt + (size_t)(n0 + crow + 64) * K + ckc8;

  // dest base per (issue, wave) is wave-uniform; HW adds lane*16B
#define STG(kt_, bb)                                                              \
  do {                                                                            \
    __builtin_amdgcn_global_load_lds(GLB_CAST(a0 + (kt_)), LDS_CAST(&as[(bb)][wid * 512]), 16, 0, 0);        \
    __builtin_amdgcn_global_load_lds(GLB_CAST(a1 + (kt_)), LDS_CAST(&as[(bb)][2048 + wid * 512]), 16, 0, 0); \
    __builtin_amdgcn_global_load_lds(GLB_CAST(b0 + (kt_)), LDS_CAST(&bs[(bb)][wid * 512]), 16, 0, 0);        \
    __builtin_amdgcn_global_load_lds(GLB_CAST(b1 + (kt_)), LDS_CAST(&bs[(bb)][2048 + wid * 512]), 16, 0, 0); \
  } while (0)

  STG(0, 0);  // prologue: tile 0 -> buffer 0

  int cur = 0;
  for (int kt = 0; kt < K; kt += 32, cur ^= 1) {
    __syncthreads();  // drains buf[cur] DMAs (staged last iter); readers of buf[cur^1] done
    const int ktn = (kt + 32 < K) ? kt + 32 : kt;  // tail: restage (junk-safe)
    STG(ktn, cur ^ 1);

    short8 afr[4], bfr[4];
#pragma unroll
    for (int mt = 0; mt < 4; ++mt)
      afr[mt] = *(const short8*)&as[cur][(wm * 32 + mt * 8 + lm) * 64 + slotA];
#pragma unroll
    for (int nt = 0; nt < 4; ++nt)
      bfr[nt] = *(const short8*)&bs[cur][(wn * 32 + nt * 8 + lm) * 64 + slotA];
#pragma unroll
    for (int mt = 0; mt < 4; ++mt)
#pragma unroll
      for (int nt = 0; nt < 4; ++nt)
        acc[mt][nt] = mfma_bf16(afr[mt], bfr[nt], acc[mt][nt]);
  }
#undef STG

  const int row0 = m0 + wm * 64 + quad * 4;
  const int col0 = n0 + wn * 64 + l16;
  if (mode == 2 && n0 >= 2048) {
    // V part -> transposed vT[(b*16+h)*64+d][t]
#pragma unroll
    for (int mt = 0; mt < 4; ++mt)
#pragma unroll
      for (int nt = 0; nt < 4; ++nt)
#pragma unroll
        for (int r = 0; r < 4; ++r) {
          const int row = row0 + mt * 16 + r;
          const int col = col0 + nt * 16;
          const int d = col & 63, hh = (col >> 6) - 32;
          const int bb = row >> 11, t = row & 2047;
          C2[((size_t)(bb * 16 + hh) * 64 + d) * T_SEQ + t] = f2bf(acc[mt][nt][r]);
        }
  } else {
    const int outN = (mode == 2) ? 2048 : N;
#pragma unroll
    for (int mt = 0; mt < 4; ++mt)
#pragma unroll
      for (int nt = 0; nt < 4; ++nt)
#pragma unroll
        for (int r = 0; r < 4; ++r) {
          const size_t off = (size_t)(row0 + mt * 16 + r) * outN + col0 + nt * 16;
          if (out_f32) ((float*)C)[off] = acc[mt][nt][r];
          else         ((short*)C)[off] = f2bf(acc[mt][nt][r]);
        }
  }
}

// ---- flash attention v3 (round-8 validated, unchanged) --------------------
// 8 waves x 128 queries/block, K+V dbuf at 50 KB LDS -> 3 blocks/CU x 8
// waves = 24 waves/CU (same TLP as 4-wave single-buffer, half the staging
// and barriers per unit work, DMA drain hidden under the tile body).
__global__ __launch_bounds__(512) void attn(const short* __restrict__ qk,
                                            const short* __restrict__ vT,
                                            short* __restrict__ y) {
  __shared__ short ks[2][64 * 64];  // [key][d], 8 chunks/row XOR-swizzled
  __shared__ short vs[2][64 * 64];  // [d][key], same swizzle
  __shared__ short ps[8][16][72];   // per-wave P [q][key]
  const int tid = threadIdx.x;
  const int wid = tid >> 6, lane = tid & 63;
  const int quad = lane >> 4, l16 = lane & 15;
  const int b = blockIdx.x >> 4, h = blockIdx.x & 15;
  const int q0 = ((int)gridDim.y - 1 - (int)blockIdx.y) * 128;  // heavy blocks first
  const int qw0 = q0 + wid * 16;

  const short* qbase = qk + (size_t)b * T_SEQ * 2048 + h * DHEAD;
  const short* kbase = qbase + DMODEL;
  const short* vtb = vT + (size_t)(b * NHEADS + h) * DHEAD * T_SEQ;
  const float SC = 0.18033688011112042f;  // 0.125 * log2(e), folded into Q

  // staging lane map: 8 waves cover all 64 rows in one issue:
  // row = wid*8 + (lane>>3), chunk = (lane&7) ^ (row&7)
  const int srl = lane >> 3;
  const int sch = ((lane & 7) ^ srl) * 8;

  // Q fragments (A-layout m=l16, k=quad*8+j), pre-scaled by SC
  short8 aq[2];
#pragma unroll
  for (int kc = 0; kc < 2; ++kc) {
    short8 raw = *(const short8*)(qbase + (size_t)(qw0 + l16) * 2048 + kc * 32 + quad * 8);
#pragma unroll
    for (int j = 0; j < 8; ++j) aq[kc][j] = f2bf(bf2f(raw[j]) * SC);
  }

  const floatx4 zero4 = {0.f, 0.f, 0.f, 0.f};
  floatx4 o[4], lacc = zero4;  // lacc: row-sum via ones-MFMA
#pragma unroll
  for (int i = 0; i < 4; ++i) o[i] = zero4;
  const short8 ones8 = {0x3F80, 0x3F80, 0x3F80, 0x3F80, 0x3F80, 0x3F80, 0x3F80, 0x3F80};

  const int kend = q0 + 128;

  // prologue: stage K/V tile 0 into buffer 0 (1 DMA each per thread)
  {
    const int row = wid * 8 + srl;
    const short* gk = kbase + (size_t)row * 2048 + sch;
    const short* gv = vtb + (size_t)row * T_SEQ + sch;
    __builtin_amdgcn_global_load_lds(GLB_CAST(gk), LDS_CAST(&ks[0][(wid * 8) * 64]), 16, 0, 0);
    __builtin_amdgcn_global_load_lds(GLB_CAST(gv), LDS_CAST(&vs[0][(wid * 8) * 64]), 16, 0, 0);
  }

  int cur = 0;
  for (int kt = 0; kt < kend; kt += 64, cur ^= 1) {
    __syncthreads();  // drains ks/vs[cur] DMA; prev tile's readers of [cur^1] done

    {  // stage next tile into the other buffer (clamped at tail: restage kt)
      const int ktn = (kt + 64 < kend) ? kt + 64 : kt;
      const int nxt = cur ^ 1;
      const int row = wid * 8 + srl;
      const short* gk = kbase + (size_t)(ktn + row) * 2048 + sch;
      const short* gv = vtb + (size_t)row * T_SEQ + ktn + sch;
      __builtin_amdgcn_global_load_lds(GLB_CAST(gk), LDS_CAST(&ks[nxt][(wid * 8) * 64]), 16, 0, 0);
      __builtin_amdgcn_global_load_lds(GLB_CAST(gv), LDS_CAST(&vs[nxt][(wid * 8) * 64]), 16, 0, 0);
    }

    // wave-uniform skip: smallest key (kt) must be <= largest query (qw0+15)
    if (kt <= qw0 + 15) {
      const short* ksc = &ks[cur][0];
      const short* vsc = &vs[cur][0];

      // S = Q K^T : 16q x 64key per wave
      floatx4 s[4];
#pragma unroll
      for (int nt = 0; nt < 4; ++nt) {
        s[nt] = zero4;
#pragma unroll
        for (int kc = 0; kc < 2; ++kc) {
          const int slot = ((kc * 4 + quad) ^ (l16 & 7)) * 8;
          const short8 bk = *(const short8*)&ksc[(nt * 16 + l16) * 64 + slot];
          s[nt] = mfma_bf16(aq[kc], bk, s[nt]);
        }
      }

      // max-free softmax: p = 2^s; zero masked keys (diagonal tiles only)
      const bool full = (kt + 63 <= qw0);  // wave-uniform
#pragma unroll
      for (int nt = 0; nt < 4; ++nt)
#pragma unroll
        for (int r = 0; r < 4; ++r) {
          float p = exp2_(s[nt][r]);
          if (!full) {
            const int key = kt + nt * 16 + l16;
            const int q = qw0 + quad * 4 + r;
            p = (key <= q) ? p : 0.f;
          }
          s[nt][r] = p;
        }

      // P (C-layout) -> per-wave LDS [q][key] (wave-internal, no barrier)
#pragma unroll
      for (int nt = 0; nt < 4; ++nt)
#pragma unroll
        for (int r = 0; r < 4; ++r)
          ps[wid][quad * 4 + r][nt * 16 + l16] = f2bf(s[nt][r]);

      // O += P V ; l += P 1
#pragma unroll
      for (int kc = 0; kc < 2; ++kc) {
        const short8 ap = *(const short8*)&ps[wid][l16][kc * 32 + quad * 8];
        lacc = mfma_bf16(ap, ones8, lacc);
#pragma unroll
        for (int d4 = 0; d4 < 4; ++d4) {
          const int slot = ((kc * 4 + quad) ^ (l16 & 7)) * 8;
          const short8 bv = *(const short8*)&vsc[(d4 * 16 + l16) * 64 + slot];
          o[d4] = mfma_bf16(ap, bv, o[d4]);
        }
      }
    }
  }

  // epilogue: O /= l
  floatx4 inv;
#pragma unroll
  for (int r = 0; r < 4; ++r) inv[r] = 1.0f / lacc[r];
#pragma unroll
  for (int d4 = 0; d4 < 4; ++d4)
#pragma unroll
    for (int r = 0; r < 4; ++r) {
      const int q = qw0 + quad * 4 + r;
      y[(size_t)(b * T_SEQ + q) * DMODEL + h * DHEAD + d4 * 16 + l16] =
          f2bf(o[d4][r] * inv[r]);
    }
}

extern "C" void kernel_launch(void* const* d_in, const int* in_sizes, int n_in,
                              void* d_out, int out_size, void* d_ws, size_t ws_size,
                              hipStream_t stream) {
  const char* x = (const char*)d_in[0];       // [4,2048,1024] fp32 (or bf16)
  const char* w_qkv = (const char*)d_in[1];   // [1024,3072]
  const char* w_proj = (const char*)d_in[2];  // [1024,1024]
  const unsigned* xs = (const unsigned*)d_in[0];

  // ws: qk(33.6M) | vT(16.8M) | wqkvT(6.3M) | wprojT(2.1M) | xbf=ybuf(16.8M) = 75.5MB
  short* qk = (short*)d_ws;                          // 8192*2048
  short* vTb = qk + (size_t)8192 * 2048;             // 64*64*2048
  short* wqkvT = vTb + (size_t)64 * 64 * 2048;       // 3072*1024
  short* wprojT = wqkvT + (size_t)3072 * 1024;       // 1024*1024
  short* xbf = wprojT + (size_t)1024 * 1024;         // 8192*1024
  short* ybuf = xbf;                                 // alias: xbf dead after gemm1

  // fused prep: conv_x (4096 blocks) + tpose wqkv (3072) + tpose wproj (1024)
  prep<<<4096 + 3072 + 1024, 256, 0, stream>>>(x, xbf, w_qkv, wqkvT, w_proj, wprojT, xs);
  {  // qkv projection with split epilogue: Q,K -> qk ; V -> vT (transposed)
    dim3 grid(3072 / 128, 8192 / 128);
    gemm128<<<grid, 256, 0, stream>>>(xbf, wqkvT, qk, vTb, 8192, 3072, 1024, 2, xs);
  }
  {
    dim3 grid(4 * NHEADS, T_SEQ / 128);  // 64 x 16, 8 waves x 128 queries
    attn<<<grid, 512, 0, stream>>>(qk, vTb, ybuf);
  }
  {
    dim3 grid(1024 / 128, 8192 / 128);
    gemm128<<<grid, 256, 0, stream>>>(ybuf, wprojT, d_out, nullptr, 8192, 1024, 1024, 1, xs);
  }
}

// Round 10
// 250.220 us; speedup vs baseline: 1.0905x; 1.0905x over previous
//
#include <hip/hip_runtime.h>
#include <hip/hip_bf16.h>
#include <cmath>

#define T_SEQ 2048
#define NHEADS 16
#define DHEAD 64
#define DMODEL 1024
#define CQKV 3072

typedef __attribute__((ext_vector_type(8))) short short8;
typedef __attribute__((ext_vector_type(8))) __bf16 bf16x8;
typedef __attribute__((ext_vector_type(4))) float floatx4;

#define LDS_CAST(p) ((__attribute__((address_space(3))) void*)(p))
#define GLB_CAST(p) ((const __attribute__((address_space(1))) void*)(p))

static __device__ __forceinline__ floatx4 mfma_bf16(short8 a, short8 b, floatx4 c) {
  return __builtin_amdgcn_mfma_f32_16x16x32_bf16(
      __builtin_bit_cast(bf16x8, a), __builtin_bit_cast(bf16x8, b), c, 0, 0, 0);
}

// fp32 -> bf16 round-to-nearest-even, bit carrier = short
static __device__ __forceinline__ short f2bf(float f) {
  union { float f; unsigned u; } x; x.f = f;
  unsigned r = x.u + 0x7FFFu + ((x.u >> 16) & 1u);
  return (short)(r >> 16);
}

static __device__ __forceinline__ float bf2f(short s) {
  return __builtin_bit_cast(float, ((unsigned)(unsigned short)s) << 16);
}

static __device__ __forceinline__ float exp2_(float x) {
#if __has_builtin(__builtin_amdgcn_exp2f)
  return __builtin_amdgcn_exp2f(x);
#else
  return exp2f(x);
#endif
}

// bf16 vs fp32 input sniff (round-1 notes). 16-of-32 exponent vote.
static __device__ __forceinline__ bool sniff_is_bf16(const unsigned* __restrict__ x) {
  int cnt = 0;
#pragma unroll
  for (int i = 0; i < 32; ++i) {
    unsigned e = (x[i] >> 7) & 0xFFu;
    cnt += (e >= 0x70u && e <= 0x8Fu) ? 1 : 0;
  }
  return cnt >= 16;
}

static __device__ __forceinline__ short8 load8f32(const char* p, size_t idx) {
  const float4* f = (const float4*)(p + idx * 4);
  float4 a = f[0], b = f[1];
  short8 r;
  r[0] = f2bf(a.x); r[1] = f2bf(a.y); r[2] = f2bf(a.z); r[3] = f2bf(a.w);
  r[4] = f2bf(b.x); r[5] = f2bf(b.y); r[6] = f2bf(b.z); r[7] = f2bf(b.w);
  return r;
}

// ---- fused preprocessing: conv_x + tpose(w_qkv) + tpose(w_proj) -----------
// blockIdx.x ranges:
//   [0, 4096)            : x -> bf16 copy/convert (8 elems/thread)
//   [4096, 4096+3072)    : w_qkv [1024,3072] -> wqkvT [3072,1024]
//   [7168, 7168+1024)    : w_proj [1024,1024] -> wprojT [1024,1024]
__global__ __launch_bounds__(256) void prep(const char* __restrict__ x,
                                            short* __restrict__ xbf,
                                            const char* __restrict__ wqkv,
                                            short* __restrict__ wqkvT,
                                            const char* __restrict__ wproj,
                                            short* __restrict__ wprojT,
                                            const unsigned* __restrict__ xs) {
  const bool isbf = sniff_is_bf16(xs);
  const int bid = blockIdx.x;
  if (bid < 4096) {
    const int i = (bid * 256 + threadIdx.x) * 8;
    if (isbf) *(short8*)(xbf + i) = *(const short8*)((const short*)x + i);
    else      *(short8*)(xbf + i) = load8f32(x, (size_t)i);
    return;
  }
  // transpose part: 32x32 tile per block
  __shared__ short tile[32][33];
  const char* w; short* wt; int N, bid2;
  if (bid < 4096 + 3072) { w = wqkv;  wt = wqkvT;  N = 3072; bid2 = bid - 4096; }
  else                   { w = wproj; wt = wprojT; N = 1024; bid2 = bid - 7168; }
  const int K = 1024;
  const int ntiles = N >> 5;
  const int n0 = (bid2 % ntiles) * 32, k0 = (bid2 / ntiles) * 32;
  const int tx = threadIdx.x & 31, ty = threadIdx.x >> 5;  // 32 x 8
#pragma unroll
  for (int i = 0; i < 4; ++i) {
    const int r = ty * 4 + i;
    const size_t off = (size_t)(k0 + r) * N + n0 + tx;
    tile[r][tx] = isbf ? ((const short*)w)[off] : f2bf(((const float*)w)[off]);
  }
  __syncthreads();
#pragma unroll
  for (int i = 0; i < 4; ++i) {
    const int r = ty * 4 + i;
    wt[(size_t)(n0 + r) * K + k0 + tx] = tile[tx][r];
  }
}

// ---- GEMM: C = A @ Bt^T, 128x128 tile, BK=64, XOR-swizzled LDS ------------
// R8-validated structure (BK=64, 2 barriers/iter, 32 KB LDS -> 5 blk/CU).
// R9 lesson: BK=32 dbuf regressed (per-barrier MFMA work halved; iteration
// overhead dominated) -- keep BK=64.
// NEW (round 10): XCD-chunked bijective blockIdx swizzle (T1/m204).
// Consecutive blocks round-robin XCDs by default, so the 24 consecutive
// N-tiles sharing one A-panel land on 8 different L2s -> A re-fetched per
// XCD (FETCH 77 MB vs 23 ideal). Chunking gives each XCD a contiguous
// bid-range (8 A-panels reused 24x from its own L2). Grids divide by 8
// (1536, 512) so the simple form is bijective.
// mode 0: C bf16 row-major [M,N]
// mode 1: C dtype per sniff (bf16 in -> bf16 out, fp32 in -> fp32 out)
// mode 2: QKV split: cols [0,2048) -> qk [M,2048]; cols [2048,3072) -> vT.
__global__ __launch_bounds__(256) void gemm128(const short* __restrict__ A,
                                               const short* __restrict__ Bt,
                                               void* __restrict__ C,
                                               short* __restrict__ C2,
                                               int M, int N, int K, int mode,
                                               const unsigned* __restrict__ xs) {
  const bool out_f32 = (mode == 1) ? !sniff_is_bf16(xs) : false;

  __shared__ short as[128 * 64];
  __shared__ short bs[128 * 64];
  const int tid = threadIdx.x;
  const int wid = tid >> 6, lane = tid & 63;
  const int quad = lane >> 4, l16 = lane & 15;
  const int wm = wid >> 1, wn = wid & 1;

  // XCD-chunked bijective swizzle: blocks on one XCD (bid mod 8) get a
  // contiguous tile range -> A-panel reuse hits that XCD's L2.
  const int gx = (int)gridDim.x;
  const int nwg = gx * (int)gridDim.y;
  int bid = (int)blockIdx.y * gx + (int)blockIdx.x;
  bid = (bid & 7) * (nwg >> 3) + (bid >> 3);
  const int m0 = (bid / gx) * 128;
  const int n0 = (bid % gx) * 128;

  // staging: issue i of wave covers rows wid*32 + i*8 .. +8 (128B rows)
  const int srl = lane >> 3;               // row within the 8-row group
  const int sch = ((lane & 7) ^ srl) * 8;  // XOR-swizzled 16B chunk (shorts)

  const floatx4 zero4 = {0.f, 0.f, 0.f, 0.f};
  floatx4 acc[4][4];
#pragma unroll
  for (int i = 0; i < 4; ++i)
#pragma unroll
    for (int j = 0; j < 4; ++j) acc[i][j] = zero4;

  for (int kt = 0; kt < K; kt += 64) {
    __syncthreads();
#pragma unroll
    for (int i = 0; i < 4; ++i) {
      const int row = wid * 32 + i * 8;
      const short* ga = A + (size_t)(m0 + row + srl) * K + kt + sch;
      const short* gb = Bt + (size_t)(n0 + row + srl) * K + kt + sch;
      __builtin_amdgcn_global_load_lds(GLB_CAST(ga), LDS_CAST(as + row * 64), 16, 0, 0);
      __builtin_amdgcn_global_load_lds(GLB_CAST(gb), LDS_CAST(bs + row * 64), 16, 0, 0);
    }
    __syncthreads();

    // fragment slot: chunk j of row R lives at slot j ^ (R&7); R&7 == l16&7
#pragma unroll
    for (int kc = 0; kc < 2; ++kc) {
      const int slot = ((kc * 4 + quad) ^ (l16 & 7)) * 8;
      short8 afr[4], bfr[4];
#pragma unroll
      for (int mt = 0; mt < 4; ++mt)
        afr[mt] = *(const short8*)&as[(wm * 64 + mt * 16 + l16) * 64 + slot];
#pragma unroll
      for (int nt = 0; nt < 4; ++nt)
        bfr[nt] = *(const short8*)&bs[(wn * 64 + nt * 16 + l16) * 64 + slot];
#pragma unroll
      for (int mt = 0; mt < 4; ++mt)
#pragma unroll
        for (int nt = 0; nt < 4; ++nt)
          acc[mt][nt] = mfma_bf16(afr[mt], bfr[nt], acc[mt][nt]);
    }
  }

  const int row0 = m0 + wm * 64 + quad * 4;
  const int col0 = n0 + wn * 64 + l16;
  if (mode == 2 && n0 >= 2048) {
    // V part -> transposed vT[(b*16+h)*64+d][t]
#pragma unroll
    for (int mt = 0; mt < 4; ++mt)
#pragma unroll
      for (int nt = 0; nt < 4; ++nt)
#pragma unroll
        for (int r = 0; r < 4; ++r) {
          const int row = row0 + mt * 16 + r;
          const int col = col0 + nt * 16;
          const int d = col & 63, hh = (col >> 6) - 32;
          const int bb = row >> 11, t = row & 2047;
          C2[((size_t)(bb * 16 + hh) * 64 + d) * T_SEQ + t] = f2bf(acc[mt][nt][r]);
        }
  } else {
    const int outN = (mode == 2) ? 2048 : N;
#pragma unroll
    for (int mt = 0; mt < 4; ++mt)
#pragma unroll
      for (int nt = 0; nt < 4; ++nt)
#pragma unroll
        for (int r = 0; r < 4; ++r) {
          const size_t off = (size_t)(row0 + mt * 16 + r) * outN + col0 + nt * 16;
          if (out_f32) ((float*)C)[off] = acc[mt][nt][r];
          else         ((short*)C)[off] = f2bf(acc[mt][nt][r]);
        }
  }
}

// ---- flash attention v3 (round-8 validated, unchanged) --------------------
// 8 waves x 128 queries/block, K+V dbuf at 50 KB LDS -> 3 blocks/CU x 8
// waves = 24 waves/CU (same TLP as 4-wave single-buffer, half the staging
// and barriers per unit work, DMA drain hidden under the tile body).
__global__ __launch_bounds__(512) void attn(const short* __restrict__ qk,
                                            const short* __restrict__ vT,
                                            short* __restrict__ y) {
  __shared__ short ks[2][64 * 64];  // [key][d], 8 chunks/row XOR-swizzled
  __shared__ short vs[2][64 * 64];  // [d][key], same swizzle
  __shared__ short ps[8][16][72];   // per-wave P [q][key]
  const int tid = threadIdx.x;
  const int wid = tid >> 6, lane = tid & 63;
  const int quad = lane >> 4, l16 = lane & 15;
  const int b = blockIdx.x >> 4, h = blockIdx.x & 15;
  const int q0 = ((int)gridDim.y - 1 - (int)blockIdx.y) * 128;  // heavy blocks first
  const int qw0 = q0 + wid * 16;

  const short* qbase = qk + (size_t)b * T_SEQ * 2048 + h * DHEAD;
  const short* kbase = qbase + DMODEL;
  const short* vtb = vT + (size_t)(b * NHEADS + h) * DHEAD * T_SEQ;
  const float SC = 0.18033688011112042f;  // 0.125 * log2(e), folded into Q

  // staging lane map: 8 waves cover all 64 rows in one issue:
  // row = wid*8 + (lane>>3), chunk = (lane&7) ^ (row&7)
  const int srl = lane >> 3;
  const int sch = ((lane & 7) ^ srl) * 8;

  // Q fragments (A-layout m=l16, k=quad*8+j), pre-scaled by SC
  short8 aq[2];
#pragma unroll
  for (int kc = 0; kc < 2; ++kc) {
    short8 raw = *(const short8*)(qbase + (size_t)(qw0 + l16) * 2048 + kc * 32 + quad * 8);
#pragma unroll
    for (int j = 0; j < 8; ++j) aq[kc][j] = f2bf(bf2f(raw[j]) * SC);
  }

  const floatx4 zero4 = {0.f, 0.f, 0.f, 0.f};
  floatx4 o[4], lacc = zero4;  // lacc: row-sum via ones-MFMA
#pragma unroll
  for (int i = 0; i < 4; ++i) o[i] = zero4;
  const short8 ones8 = {0x3F80, 0x3F80, 0x3F80, 0x3F80, 0x3F80, 0x3F80, 0x3F80, 0x3F80};

  const int kend = q0 + 128;

  // prologue: stage K/V tile 0 into buffer 0 (1 DMA each per thread)
  {
    const int row = wid * 8 + srl;
    const short* gk = kbase + (size_t)row * 2048 + sch;
    const short* gv = vtb + (size_t)row * T_SEQ + sch;
    __builtin_amdgcn_global_load_lds(GLB_CAST(gk), LDS_CAST(&ks[0][(wid * 8) * 64]), 16, 0, 0);
    __builtin_amdgcn_global_load_lds(GLB_CAST(gv), LDS_CAST(&vs[0][(wid * 8) * 64]), 16, 0, 0);
  }

  int cur = 0;
  for (int kt = 0; kt < kend; kt += 64, cur ^= 1) {
    __syncthreads();  // drains ks/vs[cur] DMA; prev tile's readers of [cur^1] done

    {  // stage next tile into the other buffer (clamped at tail: restage kt)
      const int ktn = (kt + 64 < kend) ? kt + 64 : kt;
      const int nxt = cur ^ 1;
      const int row = wid * 8 + srl;
      const short* gk = kbase + (size_t)(ktn + row) * 2048 + sch;
      const short* gv = vtb + (size_t)row * T_SEQ + ktn + sch;
      __builtin_amdgcn_global_load_lds(GLB_CAST(gk), LDS_CAST(&ks[nxt][(wid * 8) * 64]), 16, 0, 0);
      __builtin_amdgcn_global_load_lds(GLB_CAST(gv), LDS_CAST(&vs[nxt][(wid * 8) * 64]), 16, 0, 0);
    }

    // wave-uniform skip: smallest key (kt) must be <= largest query (qw0+15)
    if (kt <= qw0 + 15) {
      const short* ksc = &ks[cur][0];
      const short* vsc = &vs[cur][0];

      // S = Q K^T : 16q x 64key per wave
      floatx4 s[4];
#pragma unroll
      for (int nt = 0; nt < 4; ++nt) {
        s[nt] = zero4;
#pragma unroll
        for (int kc = 0; kc < 2; ++kc) {
          const int slot = ((kc * 4 + quad) ^ (l16 & 7)) * 8;
          const short8 bk = *(const short8*)&ksc[(nt * 16 + l16) * 64 + slot];
          s[nt] = mfma_bf16(aq[kc], bk, s[nt]);
        }
      }

      // max-free softmax: p = 2^s; zero masked keys (diagonal tiles only)
      const bool full = (kt + 63 <= qw0);  // wave-uniform
#pragma unroll
      for (int nt = 0; nt < 4; ++nt)
#pragma unroll
        for (int r = 0; r < 4; ++r) {
          float p = exp2_(s[nt][r]);
          if (!full) {
            const int key = kt + nt * 16 + l16;
            const int q = qw0 + quad * 4 + r;
            p = (key <= q) ? p : 0.f;
          }
          s[nt][r] = p;
        }

      // P (C-layout) -> per-wave LDS [q][key] (wave-internal, no barrier)
#pragma unroll
      for (int nt = 0; nt < 4; ++nt)
#pragma unroll
        for (int r = 0; r < 4; ++r)
          ps[wid][quad * 4 + r][nt * 16 + l16] = f2bf(s[nt][r]);

      // O += P V ; l += P 1
#pragma unroll
      for (int kc = 0; kc < 2; ++kc) {
        const short8 ap = *(const short8*)&ps[wid][l16][kc * 32 + quad * 8];
        lacc = mfma_bf16(ap, ones8, lacc);
#pragma unroll
        for (int d4 = 0; d4 < 4; ++d4) {
          const int slot = ((kc * 4 + quad) ^ (l16 & 7)) * 8;
          const short8 bv = *(const short8*)&vsc[(d4 * 16 + l16) * 64 + slot];
          o[d4] = mfma_bf16(ap, bv, o[d4]);
        }
      }
    }
  }

  // epilogue: O /= l
  floatx4 inv;
#pragma unroll
  for (int r = 0; r < 4; ++r) inv[r] = 1.0f / lacc[r];
#pragma unroll
  for (int d4 = 0; d4 < 4; ++d4)
#pragma unroll
    for (int r = 0; r < 4; ++r) {
      const int q = qw0 + quad * 4 + r;
      y[(size_t)(b * T_SEQ + q) * DMODEL + h * DHEAD + d4 * 16 + l16] =
          f2bf(o[d4][r] * inv[r]);
    }
}

extern "C" void kernel_launch(void* const* d_in, const int* in_sizes, int n_in,
                              void* d_out, int out_size, void* d_ws, size_t ws_size,
                              hipStream_t stream) {
  const char* x = (const char*)d_in[0];       // [4,2048,1024] fp32 (or bf16)
  const char* w_qkv = (const char*)d_in[1];   // [1024,3072]
  const char* w_proj = (const char*)d_in[2];  // [1024,1024]
  const unsigned* xs = (const unsigned*)d_in[0];

  // ws: qk(33.6M) | vT(16.8M) | wqkvT(6.3M) | wprojT(2.1M) | xbf=ybuf(16.8M) = 75.5MB
  short* qk = (short*)d_ws;                          // 8192*2048
  short* vTb = qk + (size_t)8192 * 2048;             // 64*64*2048
  short* wqkvT = vTb + (size_t)64 * 64 * 2048;       // 3072*1024
  short* wprojT = wqkvT + (size_t)3072 * 1024;       // 1024*1024
  short* xbf = wprojT + (size_t)1024 * 1024;         // 8192*1024
  short* ybuf = xbf;                                 // alias: xbf dead after gemm1

  // fused prep: conv_x (4096 blocks) + tpose wqkv (3072) + tpose wproj (1024)
  prep<<<4096 + 3072 + 1024, 256, 0, stream>>>(x, xbf, w_qkv, wqkvT, w_proj, wprojT, xs);
  {  // qkv projection with split epilogue: Q,K -> qk ; V -> vT (transposed)
    dim3 grid(3072 / 128, 8192 / 128);  // 24 x 64 = 1536 blocks (div by 8)
    gemm128<<<grid, 256, 0, stream>>>(xbf, wqkvT, qk, vTb, 8192, 3072, 1024, 2, xs);
  }
  {
    dim3 grid(4 * NHEADS, T_SEQ / 128);  // 64 x 16, 8 waves x 128 queries
    attn<<<grid, 512, 0, stream>>>(qk, vTb, ybuf);
  }
  {
    dim3 grid(1024 / 128, 8192 / 128);  // 8 x 64 = 512 blocks (div by 8)
    gemm128<<<grid, 256, 0, stream>>>(ybuf, wprojT, d_out, nullptr, 8192, 1024, 1024, 1, xs);
  }
}